// Round 13
// baseline (78.955 us; speedup 1.0000x reference)
//
#include <hip/hip_runtime.h>
#include <hip/hip_bf16.h>

// CapsuleConv2d fused, MFMA edition v12 = v11 + asm MFMA (D in VGPRs) + trans diet.
// N=4, C=64 (G=8 x IN_LEN=8), H=W=32, O=8, L=16, F=72 (G x 3x3), pad1 stride1.
//
// r11 PMC: VGPR_Count 60 + Occupancy 37% -> P[18]f32x4 lives in AGPRs
// (60+~76 = 136 unified regs/wave = 3 waves/SIMD). VOP3P can't read AGPRs ->
// v11's packed math scalarized + accvgpr_read on ~360 P accesses (the ~2x
// inst bloat behind VALUBusy 81%). v12 forces MFMA D into VGPRs via inline
// asm ("=&v", legal on gfx950's unified file per ISA doc §10), guarded by
// sched_barrier(0) + 2x s_nop 7 against MFMA->VALU read hazards.
// Also: exp -> exp2 with log2e folded into the ov scale; squash via
// v_rcp/v_rsq approx (vs slow div/sqrt sequences).
//
// prep: x fp32 -> xT per pixel [hi c0..63 | lo c0..63] (bf16 split, LDS transpose);
//       w fp32 -> wT records [hi p0..7 | lo p0..7].
// caps_main: block = (n,o,h,wtile16) = 2048; 4 waves = 4 f-quadrants (18 f).
//   Priors: one mfma per f; K-octets = exact bf16-split:
//     q0: w_hi*x_hi, q1: w_hi*x_lo, q2: w_lo*x_hi, q3: w_lo*x_lo.
//   D-layout: col=lane&15=pix, row=(lane>>4)*4+reg=l  [m89-verified].
//   sbuf slot swizzle: 2-way banks on the s-exchange.

typedef short bf16x8 __attribute__((ext_vector_type(8)));
typedef float f32x4 __attribute__((ext_vector_type(4)));
typedef float f32x2 __attribute__((ext_vector_type(2)));
typedef unsigned int uint2v __attribute__((ext_vector_type(2)));

__device__ __forceinline__ f32x4 mfma_bf16_v(bf16x8 a, bf16x8 b, f32x4 c) {
  f32x4 d;
  asm volatile("v_mfma_f32_16x16x32_bf16 %0, %1, %2, %3"
               : "=&v"(d) : "v"(a), "v"(b), "v"(c));
  return d;
}

__device__ __forceinline__ float fast_exp2(float x) {
#if __has_builtin(__builtin_amdgcn_exp2f)
  return __builtin_amdgcn_exp2f(x);
#else
  return exp2f(x);
#endif
}
__device__ __forceinline__ float fast_rcp(float x) {
#if __has_builtin(__builtin_amdgcn_rcpf)
  return __builtin_amdgcn_rcpf(x);
#else
  return 1.f / x;
#endif
}
__device__ __forceinline__ float fast_rsq(float x) {
#if __has_builtin(__builtin_amdgcn_rsqf)
  return __builtin_amdgcn_rsqf(x);
#else
  return rsqrtf(x);
#endif
}

__device__ __forceinline__ float red16(float v) {
#if __has_builtin(__builtin_amdgcn_permlane16_swap)
  uint2v r = __builtin_amdgcn_permlane16_swap(__float_as_uint(v), __float_as_uint(v),
                                              false, false);
  return __uint_as_float(r[0]) + __uint_as_float(r[1]);
#else
  return v + __shfl_xor(v, 16);
#endif
}
__device__ __forceinline__ float red32(float v) {
#if __has_builtin(__builtin_amdgcn_permlane32_swap)
  uint2v r = __builtin_amdgcn_permlane32_swap(__float_as_uint(v), __float_as_uint(v),
                                              false, false);
  return __uint_as_float(r[0]) + __uint_as_float(r[1]);
#else
  return v + __shfl_xor(v, 32);
#endif
}

__device__ __forceinline__ f32x2 red16v2(f32x2 v) {
#if __has_builtin(__builtin_amdgcn_permlane16_swap)
  uint2v r0 = __builtin_amdgcn_permlane16_swap(__float_as_uint(v.x), __float_as_uint(v.x), false, false);
  uint2v r1 = __builtin_amdgcn_permlane16_swap(__float_as_uint(v.y), __float_as_uint(v.y), false, false);
  f32x2 a = {__uint_as_float(r0[0]), __uint_as_float(r1[0])};
  f32x2 b = {__uint_as_float(r0[1]), __uint_as_float(r1[1])};
  return a + b;
#else
  return (f32x2){v.x + __shfl_xor(v.x, 16), v.y + __shfl_xor(v.y, 16)};
#endif
}
__device__ __forceinline__ f32x2 red32v2(f32x2 v) {
#if __has_builtin(__builtin_amdgcn_permlane32_swap)
  uint2v r0 = __builtin_amdgcn_permlane32_swap(__float_as_uint(v.x), __float_as_uint(v.x), false, false);
  uint2v r1 = __builtin_amdgcn_permlane32_swap(__float_as_uint(v.y), __float_as_uint(v.y), false, false);
  f32x2 a = {__uint_as_float(r0[0]), __uint_as_float(r1[0])};
  f32x2 b = {__uint_as_float(r0[1]), __uint_as_float(r1[1])};
  return a + b;
#else
  return (f32x2){v.x + __shfl_xor(v.x, 32), v.y + __shfl_xor(v.y, 32)};
#endif
}

__device__ __forceinline__ uint pack_split(float v) {
  __hip_bfloat16 hb = __float2bfloat16(v);
  float hf = __bfloat162float(hb);
  __hip_bfloat16 lb = __float2bfloat16(v - hf);
  return (uint)(*(ushort*)&hb) | ((uint)(*(ushort*)&lb) << 16);
}

__global__ __launch_bounds__(256)
void prep(const float* __restrict__ x, const float* __restrict__ w,
          ushort* __restrict__ wT, ushort* __restrict__ xT) {
  const int b = blockIdx.x;
  if (b < 128) {
    __shared__ uint lds[32 * 65];  // [pix][c], hi|lo packed
    const int n = b >> 5, h0 = b & 31;
    const float* src = x + n * 65536 + h0 * 32;
    for (int i = threadIdx.x; i < 2048; i += 256) {
      const int c = i >> 5, p = i & 31;
      lds[p * 65 + c] = pack_split(src[c * 1024 + p]);
    }
    __syncthreads();
    uint* dst = (uint*)xT + (n * 1024 + h0 * 32) * 64;
    for (int i = threadIdx.x; i < 512; i += 256) {
      const int pix = i >> 4, seg = i & 15;        // seg 0..7 hi, 8..15 lo
      const uint* row = &lds[pix * 65 + (seg & 7) * 8];
      uint4 v;
      if (seg < 8) {
        v.x = (row[0] & 0xffffu) | (row[1] << 16);
        v.y = (row[2] & 0xffffu) | (row[3] << 16);
        v.z = (row[4] & 0xffffu) | (row[5] << 16);
        v.w = (row[6] & 0xffffu) | (row[7] << 16);
      } else {
        v.x = (row[0] >> 16) | (row[1] & 0xffff0000u);
        v.y = (row[2] >> 16) | (row[3] & 0xffff0000u);
        v.z = (row[4] >> 16) | (row[5] & 0xffff0000u);
        v.w = (row[6] >> 16) | (row[7] & 0xffff0000u);
      }
      *(uint4*)(dst + pix * 64 + seg * 4) = v;
    }
  } else {
    const int t = (b - 128) * 256 + threadIdx.x;   // (o*72+f)*16+l, 9216 total
    if (t >= 9216) return;
    const float* src = w + t * 8;
    uint hi[4], lo[4];
    #pragma unroll
    for (int p2 = 0; p2 < 4; ++p2) {
      uint a = pack_split(src[p2 * 2]);
      uint c = pack_split(src[p2 * 2 + 1]);
      hi[p2] = (a & 0xffffu) | (c << 16);
      lo[p2] = (a >> 16) | (c & 0xffff0000u);
    }
    uint* dstp = (uint*)(wT + t * 16);
    *(uint4*)dstp       = make_uint4(hi[0], hi[1], hi[2], hi[3]);
    *(uint4*)(dstp + 4) = make_uint4(lo[0], lo[1], lo[2], lo[3]);
  }
}

__global__ __launch_bounds__(256, 3)
void caps_main(const ushort* __restrict__ wT, const ushort* __restrict__ xT,
               float* __restrict__ out) {
  const int b  = blockIdx.x;
  const int wt = b & 1, h = (b >> 1) & 31, o = (b >> 6) & 7, n = b >> 9;
  const int w0 = wt * 16;
  const int tid = threadIdx.x, lane = tid & 63, fq = tid >> 6;
  const int pix = lane & 15, q = lane >> 4;

  __shared__ uint  xs[54 * 68];          // 14688 B
  __shared__ float sbuf[2][4 * 256];     // 8192 B, parity-buffered s exchange

  // zacc early so the VALU-write -> MFMA-read distance is large (hazard-safe)
  f32x4 zacc = {0.f, 0.f, 0.f, 0.f};

  // ---- stage x window (uint4 copies; zero-fill pads) ----
  for (int i = tid; i < 54 * 16; i += 256) {
    const int r = i >> 4, seg = i & 15;
    const int kh = r / 18, c = r % 18;
    const int hh = h + kh - 1, ww = w0 + c - 1;
    uint4 v = make_uint4(0u, 0u, 0u, 0u);
    if ((unsigned)hh < 32u && (unsigned)ww < 32u) {
      const uint* g = (const uint*)xT + (n * 1024 + hh * 32 + ww) * 64 + seg * 4;
      v = *(const uint4*)g;
    }
    *(uint4*)&xs[r * 68 + seg * 4] = v;
  }
  __syncthreads();

  // ---- priors: 18 asm MFMAs (D in VGPRs), one per f = fq*18 + j ----
  f32x4 P[18];
  const ushort* wA = wT + ((o * 72 + fq * 18) * 16 + pix) * 16 + ((q >= 2) ? 8 : 0);
  const int xw_lane = pix * 68 + ((q & 1) ? 32 : 0);
  #pragma unroll
  for (int j = 0; j < 18; ++j) {
    const int g = fq * 2 + (j >= 9 ? 1 : 0);
    const int s = j % 9, kh = s / 3, kw = s % 3;
    const bf16x8 a  = *(const bf16x8*)(wA + j * 256);
    const bf16x8 bv = *(const bf16x8*)&xs[(kh * 18 + kw) * 68 + g * 4 + xw_lane];
    P[j] = mfma_bf16_v(a, bv, zacc);
  }
  // hazard fence: MFMA VGPR write -> VALU read needs wait states the compiler
  // won't add around inline asm. sched_barrier(0) pins ordering; 16 nop cycles.
  __builtin_amdgcn_sched_barrier(0);
  asm volatile("s_nop 7\n\ts_nop 7");
  __builtin_amdgcn_sched_barrier(0);

  // ---- routing: lane owns (pix, l = q*4 + reg), 18 f x 4 l priors in regs ----
  float c[18];
  #pragma unroll
  for (int j = 0; j < 18; ++j) c[j] = 1.f;

  const int sidx = pix * 16 + (((q + (pix >> 1)) & 3) << 2);
  #pragma unroll
  for (int it = 0; it < 3; ++it) {
    f32x4 sp = {0.f, 0.f, 0.f, 0.f};
    #pragma unroll
    for (int j = 0; j < 18; ++j) sp += P[j] * c[j];
    float* sb = sbuf[it & 1];
    *(f32x4*)&sb[fq * 256 + sidx] = sp;
    __syncthreads();
    f32x4 t = *(const f32x4*)&sb[sidx];
    #pragma unroll
    for (int k4 = 1; k4 < 4; ++k4) t += *(const f32x4*)&sb[k4 * 256 + sidx];
    // t = 8*s. qq = |s|^2 = |t|^2/64; k = sqrt(qq)/(1+qq) via rsq+rcp approx.
    f32x2 q2 = (f32x2){t.x, t.y} * (f32x2){t.x, t.y}
             + (f32x2){t.z, t.w} * (f32x2){t.z, t.w};
    float qq = red32(red16(q2.x + q2.y)) * 0.015625f;
    const float k = qq * fast_rsq(qq) * fast_rcp(1.f + qq);
    if (it < 2) {
      // ov scaled by log2e folded into the t->ov scale: delta*log2e for exp2
      const float kk = k * (0.125f * 1.44269504088896340736f);
      const f32x2 ovlo = {t.x * kk, t.y * kk}, ovhi = {t.z * kk, t.w * kk};
      #pragma unroll
      for (int jj = 0; jj < 9; ++jj) {
        const int j0 = 2 * jj, j1 = j0 + 1;
        f32x2 t0 = (f32x2){P[j0].x, P[j0].y} * ovlo
                 + (f32x2){P[j0].z, P[j0].w} * ovhi;
        f32x2 t1 = (f32x2){P[j1].x, P[j1].y} * ovlo
                 + (f32x2){P[j1].z, P[j1].w} * ovhi;
        f32x2 dd = {t0.x + t0.y, t1.x + t1.y};
        dd = red32v2(red16v2(dd));
        c[j0] += fast_exp2(dd.x);
        c[j1] += fast_exp2(dd.y);
      }
    } else if (fq == 0) {
      const float kk = k * 0.125f;
      float* op = out + ((n * 8 + o) * 16 + (q << 2)) * 1024 + h * 32 + w0 + pix;
      op[0]    = t.x * kk;
      op[1024] = t.y * kk;
      op[2048] = t.z * kk;
      op[3072] = t.w * kk;
    }
  }
}

extern "C" void kernel_launch(void* const* d_in, const int* in_sizes, int n_in,
                              void* d_out, int out_size, void* d_ws, size_t ws_size,
                              hipStream_t stream) {
  const float* x = (const float*)d_in[0];
  const float* w = (const float*)d_in[1];
  float* outp    = (float*)d_out;
  ushort* wT = (ushort*)d_ws;                   // 9216 * 32 B = 294912 B
  ushort* xT = (ushort*)((char*)d_ws + 294912); // 4096 * 256 B = 1048576 B
  prep<<<dim3(164), dim3(256), 0, stream>>>(x, w, wT, xT);
  caps_main<<<dim3(2048), dim3(256), 0, stream>>>(wT, xT, outp);
}

// Round 14
// 74.667 us; speedup vs baseline: 1.0574x; 1.0574x over previous
//
#include <hip/hip_runtime.h>
#include <hip/hip_bf16.h>

// CapsuleConv2d fused, MFMA edition v13 = v11 (best) + validated cycle diet, NO asm.
// N=4, C=64 (G=8 x IN_LEN=8), H=W=32, O=8, L=16, F=72 (G x 3x3), pad1 stride1.
//
// History: v12's asm MFMA regressed (+3.4us: asm volatile + sched_barrier blocked
// load/MFMA interleaving in the priors loop) but its transcendental diet is
// numerically validated (same absmax). v13 = v11 + that diet only:
//   - squash via v_rsq/v_rcp approx (no IEEE sqrt/div sequences)
//   - exp -> exp2 with log2e folded into the ov scale
//   - deferred /8: t = 8s, qq = |t|^2/64, out = t*k/8
//   - staging r/18 via 2 cndmask (no magic-mul divide)
// caps_main is fp32-VALU-cycle bound (r11 PMC: VALUBusy 81%, MfmaUtil 6%);
// v_pk f32 ops are 4cy on SIMD32 (FLOP-limited pipe) -- packing = decode-only win.
//
// prep: x fp32 -> xT per pixel [hi c0..63 | lo c0..63] (bf16 split, LDS transpose);
//       w fp32 -> wT records [hi p0..7 | lo p0..7].
// caps_main: block = (n,o,h,wtile16) = 2048; 4 waves = 4 f-quadrants (18 f).
//   Priors: one intrinsic mfma_f32_16x16x32_bf16 per f; K-octets = exact split:
//     q0: w_hi*x_hi, q1: w_hi*x_lo, q2: w_lo*x_hi, q3: w_lo*x_lo.
//   D-layout: col=lane&15=pix, row=(lane>>4)*4+reg=l  [m89-verified].
//   sbuf slot swizzle: 2-way banks on the s-exchange.

typedef short bf16x8 __attribute__((ext_vector_type(8)));
typedef float f32x4 __attribute__((ext_vector_type(4)));
typedef float f32x2 __attribute__((ext_vector_type(2)));
typedef unsigned int uint2v __attribute__((ext_vector_type(2)));

__device__ __forceinline__ float fast_exp2(float x) {
#if __has_builtin(__builtin_amdgcn_exp2f)
  return __builtin_amdgcn_exp2f(x);
#else
  return exp2f(x);
#endif
}
__device__ __forceinline__ float fast_rcp(float x) {
#if __has_builtin(__builtin_amdgcn_rcpf)
  return __builtin_amdgcn_rcpf(x);
#else
  return 1.f / x;
#endif
}
__device__ __forceinline__ float fast_rsq(float x) {
#if __has_builtin(__builtin_amdgcn_rsqf)
  return __builtin_amdgcn_rsqf(x);
#else
  return rsqrtf(x);
#endif
}

__device__ __forceinline__ float red16(float v) {
#if __has_builtin(__builtin_amdgcn_permlane16_swap)
  uint2v r = __builtin_amdgcn_permlane16_swap(__float_as_uint(v), __float_as_uint(v),
                                              false, false);
  return __uint_as_float(r[0]) + __uint_as_float(r[1]);
#else
  return v + __shfl_xor(v, 16);
#endif
}
__device__ __forceinline__ float red32(float v) {
#if __has_builtin(__builtin_amdgcn_permlane32_swap)
  uint2v r = __builtin_amdgcn_permlane32_swap(__float_as_uint(v), __float_as_uint(v),
                                              false, false);
  return __uint_as_float(r[0]) + __uint_as_float(r[1]);
#else
  return v + __shfl_xor(v, 32);
#endif
}

__device__ __forceinline__ f32x2 red16v2(f32x2 v) {
#if __has_builtin(__builtin_amdgcn_permlane16_swap)
  uint2v r0 = __builtin_amdgcn_permlane16_swap(__float_as_uint(v.x), __float_as_uint(v.x), false, false);
  uint2v r1 = __builtin_amdgcn_permlane16_swap(__float_as_uint(v.y), __float_as_uint(v.y), false, false);
  f32x2 a = {__uint_as_float(r0[0]), __uint_as_float(r1[0])};
  f32x2 b = {__uint_as_float(r0[1]), __uint_as_float(r1[1])};
  return a + b;
#else
  return (f32x2){v.x + __shfl_xor(v.x, 16), v.y + __shfl_xor(v.y, 16)};
#endif
}
__device__ __forceinline__ f32x2 red32v2(f32x2 v) {
#if __has_builtin(__builtin_amdgcn_permlane32_swap)
  uint2v r0 = __builtin_amdgcn_permlane32_swap(__float_as_uint(v.x), __float_as_uint(v.x), false, false);
  uint2v r1 = __builtin_amdgcn_permlane32_swap(__float_as_uint(v.y), __float_as_uint(v.y), false, false);
  f32x2 a = {__uint_as_float(r0[0]), __uint_as_float(r1[0])};
  f32x2 b = {__uint_as_float(r0[1]), __uint_as_float(r1[1])};
  return a + b;
#else
  return (f32x2){v.x + __shfl_xor(v.x, 32), v.y + __shfl_xor(v.y, 32)};
#endif
}

__device__ __forceinline__ uint pack_split(float v) {
  __hip_bfloat16 hb = __float2bfloat16(v);
  float hf = __bfloat162float(hb);
  __hip_bfloat16 lb = __float2bfloat16(v - hf);
  return (uint)(*(ushort*)&hb) | ((uint)(*(ushort*)&lb) << 16);
}

__global__ __launch_bounds__(256)
void prep(const float* __restrict__ x, const float* __restrict__ w,
          ushort* __restrict__ wT, ushort* __restrict__ xT) {
  const int b = blockIdx.x;
  if (b < 128) {
    __shared__ uint lds[32 * 65];  // [pix][c], hi|lo packed
    const int n = b >> 5, h0 = b & 31;
    const float* src = x + n * 65536 + h0 * 32;
    for (int i = threadIdx.x; i < 2048; i += 256) {
      const int c = i >> 5, p = i & 31;
      lds[p * 65 + c] = pack_split(src[c * 1024 + p]);
    }
    __syncthreads();
    uint* dst = (uint*)xT + (n * 1024 + h0 * 32) * 64;
    for (int i = threadIdx.x; i < 512; i += 256) {
      const int pix = i >> 4, seg = i & 15;        // seg 0..7 hi, 8..15 lo
      const uint* row = &lds[pix * 65 + (seg & 7) * 8];
      uint4 v;
      if (seg < 8) {
        v.x = (row[0] & 0xffffu) | (row[1] << 16);
        v.y = (row[2] & 0xffffu) | (row[3] << 16);
        v.z = (row[4] & 0xffffu) | (row[5] << 16);
        v.w = (row[6] & 0xffffu) | (row[7] << 16);
      } else {
        v.x = (row[0] >> 16) | (row[1] & 0xffff0000u);
        v.y = (row[2] >> 16) | (row[3] & 0xffff0000u);
        v.z = (row[4] >> 16) | (row[5] & 0xffff0000u);
        v.w = (row[6] >> 16) | (row[7] & 0xffff0000u);
      }
      *(uint4*)(dst + pix * 64 + seg * 4) = v;
    }
  } else {
    const int t = (b - 128) * 256 + threadIdx.x;   // (o*72+f)*16+l, 9216 total
    if (t >= 9216) return;
    const float* src = w + t * 8;
    uint hi[4], lo[4];
    #pragma unroll
    for (int p2 = 0; p2 < 4; ++p2) {
      uint a = pack_split(src[p2 * 2]);
      uint c = pack_split(src[p2 * 2 + 1]);
      hi[p2] = (a & 0xffffu) | (c << 16);
      lo[p2] = (a >> 16) | (c & 0xffff0000u);
    }
    uint* dstp = (uint*)(wT + t * 16);
    *(uint4*)dstp       = make_uint4(hi[0], hi[1], hi[2], hi[3]);
    *(uint4*)(dstp + 4) = make_uint4(lo[0], lo[1], lo[2], lo[3]);
  }
}

__global__ __launch_bounds__(256, 4)
void caps_main(const ushort* __restrict__ wT, const ushort* __restrict__ xT,
               float* __restrict__ out) {
  const int b  = blockIdx.x;
  const int wt = b & 1, h = (b >> 1) & 31, o = (b >> 6) & 7, n = b >> 9;
  const int w0 = wt * 16;
  const int tid = threadIdx.x, lane = tid & 63, fq = tid >> 6;
  const int pix = lane & 15, q = lane >> 4;

  __shared__ uint  xs[54 * 68];          // 14688 B
  __shared__ float sbuf[2][4 * 256];     // 8192 B, parity-buffered s exchange

  // ---- stage x window (uint4 copies; zero-fill pads) ----
  for (int i = tid; i < 54 * 16; i += 256) {
    const int r = i >> 4, seg = i & 15;
    const int kh = (r >= 36) ? 2 : (r >= 18 ? 1 : 0);   // cndmask, no divide
    const int c  = r - kh * 18;
    const int hh = h + kh - 1, ww = w0 + c - 1;
    uint4 v = make_uint4(0u, 0u, 0u, 0u);
    if ((unsigned)hh < 32u && (unsigned)ww < 32u) {
      const uint* g = (const uint*)xT + (n * 1024 + hh * 32 + ww) * 64 + seg * 4;
      v = *(const uint4*)g;
    }
    *(uint4*)&xs[r * 68 + seg * 4] = v;
  }
  __syncthreads();

  // ---- priors: 18 intrinsic MFMAs, one per f = fq*18 + j; exact bf16-split ----
  f32x4 P[18];
  const f32x4 zacc = {0.f, 0.f, 0.f, 0.f};
  const ushort* wA = wT + ((o * 72 + fq * 18) * 16 + pix) * 16 + ((q >= 2) ? 8 : 0);
  const int xw_lane = pix * 68 + ((q & 1) ? 32 : 0);
  #pragma unroll
  for (int j = 0; j < 18; ++j) {
    const int g = fq * 2 + (j >= 9 ? 1 : 0);
    const int s = j % 9, kh = s / 3, kw = s % 3;
    const bf16x8 a  = *(const bf16x8*)(wA + j * 256);
    const bf16x8 bv = *(const bf16x8*)&xs[(kh * 18 + kw) * 68 + g * 4 + xw_lane];
    P[j] = __builtin_amdgcn_mfma_f32_16x16x32_bf16(a, bv, zacc, 0, 0, 0);
  }

  // ---- routing: lane owns (pix, l = q*4 + reg), 18 f x 4 l priors in regs ----
  float c[18];
  #pragma unroll
  for (int j = 0; j < 18; ++j) c[j] = 1.f;

  const int sidx = pix * 16 + (((q + (pix >> 1)) & 3) << 2);
  #pragma unroll
  for (int it = 0; it < 3; ++it) {
    f32x4 sp = {0.f, 0.f, 0.f, 0.f};
    #pragma unroll
    for (int j = 0; j < 18; ++j) sp += P[j] * c[j];
    float* sb = sbuf[it & 1];
    *(f32x4*)&sb[fq * 256 + sidx] = sp;
    __syncthreads();
    f32x4 t = *(const f32x4*)&sb[sidx];
    #pragma unroll
    for (int k4 = 1; k4 < 4; ++k4) t += *(const f32x4*)&sb[k4 * 256 + sidx];
    // t = 8*s. qq = |s|^2 = |t|^2/64; k = sqrt(qq)/(1+qq) via rsq+rcp approx.
    f32x2 q2 = (f32x2){t.x, t.y} * (f32x2){t.x, t.y}
             + (f32x2){t.z, t.w} * (f32x2){t.z, t.w};
    float qq = red32(red16(q2.x + q2.y)) * 0.015625f;
    const float k = qq * fast_rsq(qq) * fast_rcp(1.f + qq);
    if (it < 2) {
      // fold 1/8 and log2e into the delta operand: dd = delta * log2e for exp2
      const float kk = k * (0.125f * 1.44269504088896340736f);
      const f32x2 ovlo = {t.x * kk, t.y * kk}, ovhi = {t.z * kk, t.w * kk};
      #pragma unroll
      for (int jj = 0; jj < 9; ++jj) {
        const int j0 = 2 * jj, j1 = j0 + 1;
        f32x2 t0 = (f32x2){P[j0].x, P[j0].y} * ovlo
                 + (f32x2){P[j0].z, P[j0].w} * ovhi;
        f32x2 t1 = (f32x2){P[j1].x, P[j1].y} * ovlo
                 + (f32x2){P[j1].z, P[j1].w} * ovhi;
        f32x2 dd = {t0.x + t0.y, t1.x + t1.y};
        dd = red32v2(red16v2(dd));
        c[j0] += fast_exp2(dd.x);
        c[j1] += fast_exp2(dd.y);
      }
    } else if (fq == 0) {
      const float kk = k * 0.125f;
      float* op = out + ((n * 8 + o) * 16 + (q << 2)) * 1024 + h * 32 + w0 + pix;
      op[0]    = t.x * kk;
      op[1024] = t.y * kk;
      op[2048] = t.z * kk;
      op[3072] = t.w * kk;
    }
  }
}

extern "C" void kernel_launch(void* const* d_in, const int* in_sizes, int n_in,
                              void* d_out, int out_size, void* d_ws, size_t ws_size,
                              hipStream_t stream) {
  const float* x = (const float*)d_in[0];
  const float* w = (const float*)d_in[1];
  float* outp    = (float*)d_out;
  ushort* wT = (ushort*)d_ws;                   // 9216 * 32 B = 294912 B
  ushort* xT = (ushort*)((char*)d_ws + 294912); // 4096 * 256 B = 1048576 B
  prep<<<dim3(164), dim3(256), 0, stream>>>(x, w, wT, xT);
  caps_main<<<dim3(2048), dim3(256), 0, stream>>>(wT, xT, outp);
}